// Round 5
// baseline (958.470 us; speedup 1.0000x reference)
//
#include <hip/hip_runtime.h>
#include <hip/hip_bf16.h>

// Single persistent fused kernel (1024 blocks x 256 thr, 4 blocks/CU guaranteed
// resident via __launch_bounds__(256,4)) with software grid barriers.
//
//  pass 1: 8 lanes/point (lane owns a float4; wave = 8 pts = 1KB contiguous/instr).
//          s = x.w + b, rm = rowmean via 3-level shfl_xor in 8-lane subgroup.
//          Store t=(s*rm, rm) [exp arg = c1*t1+c2*t2]. f64 sum(s),sum(s^2)
//          (8x lane redundancy, divided out later) -> per-block slot (no atomics).
//  bar 1 ; every block reduces the 1024 f64 pairs (agent loads; deterministic).
//  pass 2: e = exp(c1*t1+c2*t2) (no max-shift: shift-invariant, scores small --
//          validated absmax 6e-5 R1-R4). acc += x*e in registers; flush into this
//          block's part[32][32] slot (within-block device atomics; slot pre-zeroed
//          with agent stores so atomics at the coherent point see the zeros).
//          z is NOT accumulated: out = normalize(segsum(x*e)) -- the /z and /len
//          scalars cancel under L2 normalization (norm >> 1e-12 guard).
//  bar 2 ; blocks 0..31: block b reduces part[*][b][*] (agent loads), L2-normalizes,
//          writes out[b][0..31].

#define NB  1024
#define TPB 256

__device__ __forceinline__ void grid_barrier(int* cnt, int* flag) {
  __syncthreads();
  if (threadIdx.x == 0) {
    __threadfence();                      // release my writes to the coherent point
    if (atomicAdd(cnt, 1) == NB - 1) {
      __hip_atomic_store(flag, 1, __ATOMIC_RELEASE, __HIP_MEMORY_SCOPE_AGENT);
    } else {
      int it = 0;
      while (__hip_atomic_load(flag, __ATOMIC_ACQUIRE, __HIP_MEMORY_SCOPE_AGENT) == 0) {
        __builtin_amdgcn_s_sleep(2);
        if (++it > (1 << 24)) break;      // bounded spin: fail loud, not hung
      }
    }
  }
  __syncthreads();
}

__global__ void k_zero(int* bar) {
  if (threadIdx.x < 4) bar[threadIdx.x] = 0;
}

__global__ __launch_bounds__(TPB, 4) void k_fused(
    const float* __restrict__ x, const float* __restrict__ w,
    const float* __restrict__ bptr, const float* __restrict__ gptr,
    const float* __restrict__ betap, const int* __restrict__ seg,
    float2* __restrict__ t, double* __restrict__ sumsp,
    float* __restrict__ part, int* __restrict__ bar,
    float* __restrict__ out, int N, int chunk) {

  const int tid  = threadIdx.x;
  const int lane = tid & 63;
  const int sub  = lane >> 3;     // point slot in the wave's 8-point batch
  const int cg   = lane & 7;      // which float4 of the point
  const int bid  = blockIdx.x;
  const int wib  = tid >> 6;      // wave-in-block

  // zero this block's part slot with AGENT stores (device atomics later must see it)
  float* mypart = part + (size_t)bid * 1024;
  for (int i = tid; i < 1024; i += TPB)
    __hip_atomic_store(&mypart[i], 0.0f, __ATOMIC_RELAXED, __HIP_MEMORY_SCOPE_AGENT);

  const int gwid = bid * (TPB / 64) + wib;
  int p0 = gwid * chunk;
  int p1 = p0 + chunk; if (p1 > N) p1 = N;
  const bool active = (p0 < N);

  const float4* x4 = reinterpret_cast<const float4*>(x);
  const float4 w4 = reinterpret_cast<const float4*>(w)[cg];
  const float bv = bptr[0];

  // ---------------- pass 1 ----------------
  double accS = 0.0, accS2 = 0.0;
  if (active) {
    int nb8 = (p1 - p0) >> 3;
    int pb = p0;
#pragma unroll 4
    for (int it = 0; it < nb8; ++it, pb += 8) {
      int p = pb + sub;
      float4 xv = x4[(size_t)p * 8 + cg];
      float d = fmaf(xv.x, w4.x, fmaf(xv.y, w4.y, fmaf(xv.z, w4.z, xv.w * w4.w)));
      float r = (xv.x + xv.y) + (xv.z + xv.w);
      d += __shfl_xor(d, 1);  r += __shfl_xor(r, 1);
      d += __shfl_xor(d, 2);  r += __shfl_xor(r, 2);
      d += __shfl_xor(d, 4);  r += __shfl_xor(r, 4);
      float s = d + bv;
      float rm = r * 0.03125f;
      if (cg == 0) t[p] = make_float2(s * rm, rm);
      accS  += (double)s;
      accS2 += (double)s * (double)s;
    }
    if (pb < p1) {                          // tail batch (last active wave only)
      int p = pb + sub;
      bool valid = (p < p1);
      int pc = valid ? p : p1 - 1;
      float4 xv = x4[(size_t)pc * 8 + cg];
      float d = fmaf(xv.x, w4.x, fmaf(xv.y, w4.y, fmaf(xv.z, w4.z, xv.w * w4.w)));
      float r = (xv.x + xv.y) + (xv.z + xv.w);
      d += __shfl_xor(d, 1);  r += __shfl_xor(r, 1);
      d += __shfl_xor(d, 2);  r += __shfl_xor(r, 2);
      d += __shfl_xor(d, 4);  r += __shfl_xor(r, 4);
      float s = d + bv;
      float rm = r * 0.03125f;
      if (valid) {
        if (cg == 0) t[p] = make_float2(s * rm, rm);
        accS  += (double)s;
        accS2 += (double)s * (double)s;
      }
    }
  }
#pragma unroll
  for (int off = 32; off > 0; off >>= 1) {
    accS  += __shfl_down(accS, off, 64);
    accS2 += __shfl_down(accS2, off, 64);
  }
  __shared__ double lds[8];
  if (lane == 0) { lds[wib * 2] = accS; lds[wib * 2 + 1] = accS2; }
  __syncthreads();
  if (tid == 0) {
    sumsp[bid * 2]     = lds[0] + lds[2] + lds[4] + lds[6];
    sumsp[bid * 2 + 1] = lds[1] + lds[3] + lds[5] + lds[7];
  }

  grid_barrier(&bar[0], &bar[1]);

  // every block reduces all 1024 partial pairs (deterministic order; agent loads
  // bypass the non-coherent per-XCD caches)
  {
    double a = 0.0, c = 0.0;
    for (int k = tid; k < NB; k += TPB) {
      a += __hip_atomic_load(&sumsp[k * 2],     __ATOMIC_RELAXED, __HIP_MEMORY_SCOPE_AGENT);
      c += __hip_atomic_load(&sumsp[k * 2 + 1], __ATOMIC_RELAXED, __HIP_MEMORY_SCOPE_AGENT);
    }
#pragma unroll
    for (int off = 32; off > 0; off >>= 1) {
      a += __shfl_down(a, off, 64);
      c += __shfl_down(c, off, 64);
    }
    if (lane == 0) { lds[wib * 2] = a; lds[wib * 2 + 1] = c; }
  }
  __syncthreads();
  const double S  = lds[0] + lds[2] + lds[4] + lds[6];
  const double S2 = lds[1] + lds[3] + lds[5] + lds[7];
  const double invCnt = 1.0 / (8.0 * (double)N);     // 8x lane redundancy
  const double mu  = S * invCnt;
  const double var = S2 * invCnt - mu * mu;
  const float inv = (float)(1.0 / sqrt(var + 1e-5));
  const float c1f = gptr[0] * inv;                   // exp arg = c1*t1 + c2*t2
  const float c2f = betap[0] - c1f * (float)mu;

  // ---------------- pass 2 ----------------
  if (active) {
    float4 acc = make_float4(0.f, 0.f, 0.f, 0.f);
    const int segA = seg[p0];
    const int segB = seg[p1 - 1];
    if (segA == segB) {
      // fast path: whole chunk one segment (~99% of waves)
      int nb8 = (p1 - p0) >> 3;
      int pb = p0;
#pragma unroll 4
      for (int it = 0; it < nb8; ++it, pb += 8) {
        int p = pb + sub;
        float2 tv = t[p];
        float4 xv = x4[(size_t)p * 8 + cg];
        float e = __expf(fmaf(c1f, tv.x, c2f * tv.y));
        acc.x = fmaf(xv.x, e, acc.x);
        acc.y = fmaf(xv.y, e, acc.y);
        acc.z = fmaf(xv.z, e, acc.z);
        acc.w = fmaf(xv.w, e, acc.w);
      }
      if (pb < p1) {
        int p = pb + sub;
        bool valid = (p < p1);
        int pc = valid ? p : p1 - 1;
        float2 tv = t[pc];
        float4 xv = x4[(size_t)pc * 8 + cg];
        float e = valid ? __expf(fmaf(c1f, tv.x, c2f * tv.y)) : 0.f;
        acc.x = fmaf(xv.x, e, acc.x);
        acc.y = fmaf(xv.y, e, acc.y);
        acc.z = fmaf(xv.z, e, acc.z);
        acc.w = fmaf(xv.w, e, acc.w);
      }
#pragma unroll
      for (int off = 8; off < 64; off <<= 1) {
        acc.x += __shfl_xor(acc.x, off);
        acc.y += __shfl_xor(acc.y, off);
        acc.z += __shfl_xor(acc.z, off);
        acc.w += __shfl_xor(acc.w, off);
      }
      if (sub == 0) {
        atomicAdd(&mypart[segA * 32 + cg * 4 + 0], acc.x);
        atomicAdd(&mypart[segA * 32 + cg * 4 + 1], acc.y);
        atomicAdd(&mypart[segA * 32 + cg * 4 + 2], acc.z);
        atomicAdd(&mypart[segA * 32 + cg * 4 + 3], acc.w);
      }
    } else {
      // slow path: chunk crosses a segment boundary (~31 waves)
      int curSeg = segA;
      for (int pb = p0; pb < p1; pb += 8) {
        int p = pb + sub;
        bool valid = (p < p1);
        int pc = valid ? p : p1 - 1;
        int sg = seg[pc];
        float2 tv = t[pc];
        float4 xv = x4[(size_t)pc * 8 + cg];
        float e = valid ? __expf(fmaf(c1f, tv.x, c2f * tv.y)) : 0.f;
        if (sg != curSeg) {
          atomicAdd(&mypart[curSeg * 32 + cg * 4 + 0], acc.x);
          atomicAdd(&mypart[curSeg * 32 + cg * 4 + 1], acc.y);
          atomicAdd(&mypart[curSeg * 32 + cg * 4 + 2], acc.z);
          atomicAdd(&mypart[curSeg * 32 + cg * 4 + 3], acc.w);
          acc = make_float4(0.f, 0.f, 0.f, 0.f);
          curSeg = sg;
        }
        acc.x = fmaf(xv.x, e, acc.x);
        acc.y = fmaf(xv.y, e, acc.y);
        acc.z = fmaf(xv.z, e, acc.z);
        acc.w = fmaf(xv.w, e, acc.w);
      }
      atomicAdd(&mypart[curSeg * 32 + cg * 4 + 0], acc.x);
      atomicAdd(&mypart[curSeg * 32 + cg * 4 + 1], acc.y);
      atomicAdd(&mypart[curSeg * 32 + cg * 4 + 2], acc.z);
      atomicAdd(&mypart[curSeg * 32 + cg * 4 + 3], acc.w);
    }
  }

  grid_barrier(&bar[2], &bar[3]);

  // ---------------- final: blocks 0..31, one segment each ----------------
  if (bid < 32) {
    const int b = bid;
    __shared__ float fl[8][32];
    const int c = tid & 31, j = tid >> 5;
    float pc = 0.f;
    for (int k = j; k < NB; k += 8)
      pc += __hip_atomic_load(&part[(size_t)k * 1024 + b * 32 + c],
                              __ATOMIC_RELAXED, __HIP_MEMORY_SCOPE_AGENT);
    fl[j][c] = pc;
    __syncthreads();
    if (tid < 32) {
      float v = 0.f;
#pragma unroll
      for (int jj = 0; jj < 8; ++jj) v += fl[jj][tid];
      float sq = v * v;
#pragma unroll
      for (int off = 16; off > 0; off >>= 1) sq += __shfl_xor(sq, off);
      float norm = sqrtf(sq);
      out[b * 32 + tid] = v / fmaxf(norm, 1e-12f);   // z & len cancel under normalize
    }
  }
}

extern "C" void kernel_launch(void* const* d_in, const int* in_sizes, int n_in,
                              void* d_out, int out_size, void* d_ws, size_t ws_size,
                              hipStream_t stream) {
  const float* x     = (const float*)d_in[0];
  const float* w     = (const float*)d_in[1];
  const float* b     = (const float*)d_in[2];
  const float* gamma = (const float*)d_in[3];
  const float* beta  = (const float*)d_in[4];
  const int* seg     = (const int*)d_in[6];
  int N = in_sizes[6];          // 3,170,000
  float* out = (float*)d_out;

  char* ws = (char*)d_ws;
  int*    bar   = (int*)ws;                            // 4 ints
  double* sumsp = (double*)(ws + 256);                 // NB*2 doubles (16 KB)
  float*  part  = (float*)(ws + 256 + 16384);          // NB*32*32 floats (4 MB)
  float2* t     = (float2*)(ws + 256 + 16384 + (size_t)NB * 1024 * 4);  // N float2

  const int nWaves = NB * (TPB / 64);                  // 4096
  int chunk = (N + nWaves - 1) / nWaves;
  chunk = (chunk + 7) & ~7;                            // multiple of 8

  k_zero<<<1, 64, 0, stream>>>(bar);
  k_fused<<<NB, TPB, 0, stream>>>(x, w, b, gamma, beta, seg, t, sumsp, part, bar,
                                  out, N, chunk);
}

// Round 6
// 182.872 us; speedup vs baseline: 5.2412x; 5.2412x over previous
//
#include <hip/hip_runtime.h>
#include <hip/hip_bf16.h>

// R6: back to separate kernels (R4 skeleton, best 252us), t-buffer ELIMINATED.
//  k_zero : zero sums (2 f64) + pooled (1024 f32).
//  k_stats: thread-per-point (R1-proven ~85us @5.1TB/s): 8 independent float4
//           loads, s = x.w + b; f64 sum(s), sum(s^2) -> wave+block reduce ->
//           2 atomics/block. No stores to ws in the loop.
//  k_pool : 8 lanes/point (lane owns a float4; wave = 8 pts = 1KB/instr).
//           Recomputes s and rowmean from x via 3-level shfl_xor (R2-style --
//           R2 beat R3's t-load, and ws round-trips are implicated in every
//           unexplained slowdown). e = exp((c1*s+c2)*rm), no max-shift
//           (shift-invariant; validated absmax 6e-5 R1-R5). acc += x*e in
//           registers; z NOT accumulated (z and len cancel under L2 normalize,
//           validated R5). Segment-uniform fast path (~99% of waves); slow path
//           for the ~31 boundary waves. Flush = 32 global atomics per wave.
//  k_final: L2-normalize segsum directly.

#define TPB 256
#define NBLK 2048

__global__ void k_zero(double* __restrict__ sums, float* __restrict__ pooled) {
  int tid = threadIdx.x;
  if (tid < 2) sums[tid] = 0.0;
  for (int i = tid; i < 1024; i += TPB) pooled[i] = 0.f;
}

__global__ __launch_bounds__(TPB) void k_stats(
    const float* __restrict__ x, const float* __restrict__ w,
    const float* __restrict__ bptr, double* __restrict__ sums, int N) {
  int tid = blockIdx.x * blockDim.x + threadIdx.x;
  int stride = gridDim.x * blockDim.x;
  float wreg[32];
#pragma unroll
  for (int j = 0; j < 32; ++j) wreg[j] = w[j];
  const float bv = bptr[0];
  double accS = 0.0, accS2 = 0.0;
  for (int p = tid; p < N; p += stride) {
    const float4* xp = reinterpret_cast<const float4*>(x) + (size_t)p * 8;
    float dot = 0.f;
#pragma unroll
    for (int q = 0; q < 8; ++q) {
      float4 v = xp[q];
      dot += v.x * wreg[4*q] + v.y * wreg[4*q+1] + v.z * wreg[4*q+2] + v.w * wreg[4*q+3];
    }
    float s = dot + bv;
    accS  += (double)s;
    accS2 += (double)s * (double)s;
  }
#pragma unroll
  for (int off = 32; off > 0; off >>= 1) {
    accS  += __shfl_down(accS, off, 64);
    accS2 += __shfl_down(accS2, off, 64);
  }
  __shared__ double lds[8];
  int wid = threadIdx.x >> 6;
  if ((threadIdx.x & 63) == 0) { lds[wid*2] = accS; lds[wid*2+1] = accS2; }
  __syncthreads();
  if (threadIdx.x == 0) {
    double a = lds[0] + lds[2] + lds[4] + lds[6];
    double c = lds[1] + lds[3] + lds[5] + lds[7];
    atomicAdd(&sums[0], a);
    atomicAdd(&sums[1], c);
  }
}

__global__ __launch_bounds__(TPB) void k_pool(
    const float* __restrict__ x, const int* __restrict__ seg,
    const float* __restrict__ w, const float* __restrict__ bptr,
    const double* __restrict__ sums, const float* __restrict__ gptr,
    const float* __restrict__ betap, float* __restrict__ pooled,
    int N, int chunk) {
  double mu  = sums[0] / (double)N;
  double var = sums[1] / (double)N - mu * mu;
  float inv = (float)(1.0 / sqrt(var + 1e-5));
  const float c1 = gptr[0] * inv;                 // s_bn = c1*s + c2
  const float c2 = betap[0] - c1 * (float)mu;

  const int lane = threadIdx.x & 63;
  const int sub  = lane >> 3;      // point slot within the wave's 8-point batch
  const int cg   = lane & 7;       // which float4 of the point
  const float4 w4 = reinterpret_cast<const float4*>(w)[cg];
  const float bv = bptr[0];

  int gid = blockIdx.x * (TPB >> 6) + (threadIdx.x >> 6);
  int p0 = gid * chunk;                     // chunk is a multiple of 8
  if (p0 >= N) return;
  int p1 = p0 + chunk; if (p1 > N) p1 = N;

  const float4* x4 = reinterpret_cast<const float4*>(x);
  float4 acc = make_float4(0.f, 0.f, 0.f, 0.f);
  const int segA = seg[p0];
  const int segB = seg[p1 - 1];

  if (segA == segB) {
    // ---- fast path: whole chunk in one segment ----
    int nfull = (p1 - p0) & ~7;
    int pb = p0;
#pragma unroll 8
    for (; pb < p0 + nfull; pb += 8) {
      int p = pb + sub;
      float4 xv = x4[(size_t)p * 8 + cg];
      float d = fmaf(xv.x, w4.x, fmaf(xv.y, w4.y, fmaf(xv.z, w4.z, xv.w * w4.w)));
      float r = (xv.x + xv.y) + (xv.z + xv.w);
      d += __shfl_xor(d, 1);  r += __shfl_xor(r, 1);
      d += __shfl_xor(d, 2);  r += __shfl_xor(r, 2);
      d += __shfl_xor(d, 4);  r += __shfl_xor(r, 4);
      float e = __expf(fmaf(c1, d + bv, c2) * (r * 0.03125f));
      acc.x = fmaf(xv.x, e, acc.x);
      acc.y = fmaf(xv.y, e, acc.y);
      acc.z = fmaf(xv.z, e, acc.z);
      acc.w = fmaf(xv.w, e, acc.w);
    }
    if (pb < p1) {                 // tail batch (only if N%8 != 0)
      int p = pb + sub;
      bool valid = (p < p1);
      int pc = valid ? p : p1 - 1;
      float4 xv = x4[(size_t)pc * 8 + cg];
      float d = fmaf(xv.x, w4.x, fmaf(xv.y, w4.y, fmaf(xv.z, w4.z, xv.w * w4.w)));
      float r = (xv.x + xv.y) + (xv.z + xv.w);
      d += __shfl_xor(d, 1);  r += __shfl_xor(r, 1);
      d += __shfl_xor(d, 2);  r += __shfl_xor(r, 2);
      d += __shfl_xor(d, 4);  r += __shfl_xor(r, 4);
      float e = valid ? __expf(fmaf(c1, d + bv, c2) * (r * 0.03125f)) : 0.f;
      acc.x = fmaf(xv.x, e, acc.x);
      acc.y = fmaf(xv.y, e, acc.y);
      acc.z = fmaf(xv.z, e, acc.z);
      acc.w = fmaf(xv.w, e, acc.w);
    }
#pragma unroll
    for (int off = 8; off < 64; off <<= 1) {   // reduce across the 8 point slots
      acc.x += __shfl_xor(acc.x, off);
      acc.y += __shfl_xor(acc.y, off);
      acc.z += __shfl_xor(acc.z, off);
      acc.w += __shfl_xor(acc.w, off);
    }
    if (sub == 0) {
      atomicAdd(&pooled[segA * 32 + cg * 4 + 0], acc.x);
      atomicAdd(&pooled[segA * 32 + cg * 4 + 1], acc.y);
      atomicAdd(&pooled[segA * 32 + cg * 4 + 2], acc.z);
      atomicAdd(&pooled[segA * 32 + cg * 4 + 3], acc.w);
    }
  } else {
    // ---- slow path: chunk crosses a segment boundary (~31 waves total) ----
    int curSeg = segA;
    for (int pb = p0; pb < p1; pb += 8) {
      int p = pb + sub;
      bool valid = (p < p1);
      int pc = valid ? p : p1 - 1;
      int sg = seg[pc];
      float4 xv = x4[(size_t)pc * 8 + cg];
      float d = fmaf(xv.x, w4.x, fmaf(xv.y, w4.y, fmaf(xv.z, w4.z, xv.w * w4.w)));
      float r = (xv.x + xv.y) + (xv.z + xv.w);
      d += __shfl_xor(d, 1);  r += __shfl_xor(r, 1);
      d += __shfl_xor(d, 2);  r += __shfl_xor(r, 2);
      d += __shfl_xor(d, 4);  r += __shfl_xor(r, 4);
      float e = valid ? __expf(fmaf(c1, d + bv, c2) * (r * 0.03125f)) : 0.f;
      if (sg != curSeg) {
        atomicAdd(&pooled[curSeg * 32 + cg * 4 + 0], acc.x);
        atomicAdd(&pooled[curSeg * 32 + cg * 4 + 1], acc.y);
        atomicAdd(&pooled[curSeg * 32 + cg * 4 + 2], acc.z);
        atomicAdd(&pooled[curSeg * 32 + cg * 4 + 3], acc.w);
        acc = make_float4(0.f, 0.f, 0.f, 0.f);
        curSeg = sg;
      }
      acc.x = fmaf(xv.x, e, acc.x);
      acc.y = fmaf(xv.y, e, acc.y);
      acc.z = fmaf(xv.z, e, acc.z);
      acc.w = fmaf(xv.w, e, acc.w);
    }
    atomicAdd(&pooled[curSeg * 32 + cg * 4 + 0], acc.x);
    atomicAdd(&pooled[curSeg * 32 + cg * 4 + 1], acc.y);
    atomicAdd(&pooled[curSeg * 32 + cg * 4 + 2], acc.z);
    atomicAdd(&pooled[curSeg * 32 + cg * 4 + 3], acc.w);
  }
}

__global__ void k_final(const float* __restrict__ pooled, float* __restrict__ out) {
  int tid = threadIdx.x;                 // 1024 threads, one per out element
  float v = pooled[tid];
  float sq = v * v;
#pragma unroll
  for (int off = 16; off > 0; off >>= 1) sq += __shfl_xor(sq, off, 32);
  float norm = sqrtf(sq);
  out[tid] = v / fmaxf(norm, 1e-30f);    // z & len cancel under normalize (R5-validated)
}

extern "C" void kernel_launch(void* const* d_in, const int* in_sizes, int n_in,
                              void* d_out, int out_size, void* d_ws, size_t ws_size,
                              hipStream_t stream) {
  const float* x     = (const float*)d_in[0];
  const float* w     = (const float*)d_in[1];
  const float* b     = (const float*)d_in[2];
  const float* gamma = (const float*)d_in[3];
  const float* beta  = (const float*)d_in[4];
  const int* seg     = (const int*)d_in[6];
  int N = in_sizes[6];          // 3,170,000
  float* out = (float*)d_out;

  char* ws = (char*)d_ws;
  double* sums   = (double*)ws;              // 2 doubles
  float*  pooled = (float*)(ws + 64);        // 1024 floats

  const int nWaves = NBLK * (TPB / 64);      // 8192
  int chunk = (N + nWaves - 1) / nWaves;
  chunk = (chunk + 7) & ~7;                  // multiple of 8

  k_zero <<<1, TPB, 0, stream>>>(sums, pooled);
  k_stats<<<NBLK, TPB, 0, stream>>>(x, w, b, sums, N);
  k_pool <<<NBLK, TPB, 0, stream>>>(x, seg, w, b, sums, gamma, beta, pooled, N, chunk);
  k_final<<<1, 1024, 0, stream>>>(pooled, out);
}

// Round 8
// 173.427 us; speedup vs baseline: 5.5266x; 1.0545x over previous
//
#include <hip/hip_runtime.h>
#include <hip/hip_bf16.h>

// R8 = R7 with the DPP ctrl made a template parameter (builtin requires a
// constant integer). Structure:
//  k_stats: thread-per-point, 8x float4 loads, s = x.w+b; f64 partials ->
//           per-block plain stores (no atomics, no pre-zero); block 0 zeroes pooled.
//  k_pool : 8 lanes/point; recompute s,rm from x; 8-lane sums via DPP
//           (quad_perm xor1, xor2, row_half_mirror = lane^7): 3 VALU adds,
//           zero DS ops in the hot loop. e = exp((c1*s+c2)*rm) (no max-shift:
//           shift-invariant, scores small; absmax 6e-5 R1-R6). acc += x*e in
//           registers; z/len NOT accumulated (cancel under L2 normalize).
//           Segment-uniform fast path; slow path for ~31 boundary waves.
//  k_final: L2-normalize.

#define TPB 256
#define NBLK 2048

template <int CTRL>
__device__ __forceinline__ float dpp_add(float v) {
  int sh = __builtin_amdgcn_update_dpp(
      0, __builtin_bit_cast(int, v), CTRL, 0xF, 0xF, true);
  return v + __builtin_bit_cast(float, sh);
}
// xor1 = quad_perm[1,0,3,2] = 0xB1 ; xor2 = quad_perm[2,3,0,1] = 0x4E ;
// lane^7 completes the 8-lane sum = ROW_HALF_MIRROR = 0x141

__device__ __forceinline__ float sub8_sum(float v) {
  v = dpp_add<0xB1>(v);
  v = dpp_add<0x4E>(v);
  v = dpp_add<0x141>(v);
  return v;
}

__global__ __launch_bounds__(TPB) void k_stats(
    const float* __restrict__ x, const float* __restrict__ w,
    const float* __restrict__ bptr, double* __restrict__ sumsp,
    float* __restrict__ pooled, int N) {
  if (blockIdx.x == 0) {            // zero pooled (only k_pool touches it later)
    for (int i = threadIdx.x; i < 1024; i += TPB) pooled[i] = 0.f;
  }
  int tid = blockIdx.x * blockDim.x + threadIdx.x;
  int stride = gridDim.x * blockDim.x;
  float wreg[32];
#pragma unroll
  for (int j = 0; j < 32; ++j) wreg[j] = w[j];
  const float bv = bptr[0];
  double accS = 0.0, accS2 = 0.0;
#pragma unroll 2
  for (int p = tid; p < N; p += stride) {
    const float4* xp = reinterpret_cast<const float4*>(x) + (size_t)p * 8;
    float dot = 0.f;
#pragma unroll
    for (int q = 0; q < 8; ++q) {
      float4 v = xp[q];
      dot += v.x * wreg[4*q] + v.y * wreg[4*q+1] + v.z * wreg[4*q+2] + v.w * wreg[4*q+3];
    }
    float s = dot + bv;
    accS  += (double)s;
    accS2 += (double)s * (double)s;
  }
#pragma unroll
  for (int off = 32; off > 0; off >>= 1) {
    accS  += __shfl_down(accS, off, 64);
    accS2 += __shfl_down(accS2, off, 64);
  }
  __shared__ double lds[8];
  int wid = threadIdx.x >> 6;
  if ((threadIdx.x & 63) == 0) { lds[wid*2] = accS; lds[wid*2+1] = accS2; }
  __syncthreads();
  if (threadIdx.x == 0) {
    sumsp[blockIdx.x * 2]     = lds[0] + lds[2] + lds[4] + lds[6];
    sumsp[blockIdx.x * 2 + 1] = lds[1] + lds[3] + lds[5] + lds[7];
  }
}

__global__ __launch_bounds__(TPB) void k_pool(
    const float* __restrict__ x, const int* __restrict__ seg,
    const float* __restrict__ w, const float* __restrict__ bptr,
    const double* __restrict__ sumsp, const float* __restrict__ gptr,
    const float* __restrict__ betap, float* __restrict__ pooled,
    int N, int chunk) {
  const int tid = threadIdx.x;
  // reduce the 2048 per-block stat partials (32KB, L3-hot; deterministic ->
  // identical mu/var in every block). Each wave reduces independently, then
  // broadcast from lane 0 -- no LDS needed.
  double a = 0.0, c = 0.0;
  for (int k = tid & 63; k < NBLK; k += 64) {
    a += sumsp[k * 2];
    c += sumsp[k * 2 + 1];
  }
#pragma unroll
  for (int off = 32; off > 0; off >>= 1) {
    a += __shfl_down(a, off, 64);
    c += __shfl_down(c, off, 64);
  }
  a = __shfl(a, 0, 64);
  c = __shfl(c, 0, 64);
  const double mu  = a / (double)N;
  const double var = c / (double)N - mu * mu;
  const float inv = (float)(1.0 / sqrt(var + 1e-5));
  const float c1 = gptr[0] * inv;                 // s_bn = c1*s + c2
  const float c2 = betap[0] - c1 * (float)mu;

  const int lane = tid & 63;
  const int sub  = lane >> 3;      // point slot within the wave's 8-point batch
  const int cg   = lane & 7;       // which float4 of the point
  const float4 w4 = reinterpret_cast<const float4*>(w)[cg];
  const float bv = bptr[0];

  int gid = blockIdx.x * (TPB >> 6) + (tid >> 6);
  int p0 = gid * chunk;                     // chunk is a multiple of 8
  if (p0 >= N) return;
  int p1 = p0 + chunk; if (p1 > N) p1 = N;

  const float4* x4 = reinterpret_cast<const float4*>(x);
  float4 acc = make_float4(0.f, 0.f, 0.f, 0.f);
  const int segA = seg[p0];
  const int segB = seg[p1 - 1];

  if (segA == segB) {
    // ---- fast path: whole chunk in one segment; DPP-only reductions ----
    int nfull = (p1 - p0) & ~7;
    int pb = p0;
#pragma unroll 8
    for (; pb < p0 + nfull; pb += 8) {
      int p = pb + sub;
      float4 xv = x4[(size_t)p * 8 + cg];
      float d = fmaf(xv.x, w4.x, fmaf(xv.y, w4.y, fmaf(xv.z, w4.z, xv.w * w4.w)));
      float r = (xv.x + xv.y) + (xv.z + xv.w);
      d = sub8_sum(d);
      r = sub8_sum(r);
      float e = __expf(fmaf(c1, d + bv, c2) * (r * 0.03125f));
      acc.x = fmaf(xv.x, e, acc.x);
      acc.y = fmaf(xv.y, e, acc.y);
      acc.z = fmaf(xv.z, e, acc.z);
      acc.w = fmaf(xv.w, e, acc.w);
    }
    if (pb < p1) {                 // tail batch (only the single last active wave)
      int p = pb + sub;
      bool valid = (p < p1);
      int pc = valid ? p : p1 - 1;
      float4 xv = x4[(size_t)pc * 8 + cg];
      float d = fmaf(xv.x, w4.x, fmaf(xv.y, w4.y, fmaf(xv.z, w4.z, xv.w * w4.w)));
      float r = (xv.x + xv.y) + (xv.z + xv.w);
      d = sub8_sum(d);
      r = sub8_sum(r);
      float e = valid ? __expf(fmaf(c1, d + bv, c2) * (r * 0.03125f)) : 0.f;
      acc.x = fmaf(xv.x, e, acc.x);
      acc.y = fmaf(xv.y, e, acc.y);
      acc.z = fmaf(xv.z, e, acc.z);
      acc.w = fmaf(xv.w, e, acc.w);
    }
#pragma unroll
    for (int off = 8; off < 64; off <<= 1) {   // reduce across the 8 point slots
      acc.x += __shfl_xor(acc.x, off);
      acc.y += __shfl_xor(acc.y, off);
      acc.z += __shfl_xor(acc.z, off);
      acc.w += __shfl_xor(acc.w, off);
    }
    if (sub == 0) {
      atomicAdd(&pooled[segA * 32 + cg * 4 + 0], acc.x);
      atomicAdd(&pooled[segA * 32 + cg * 4 + 1], acc.y);
      atomicAdd(&pooled[segA * 32 + cg * 4 + 2], acc.z);
      atomicAdd(&pooled[segA * 32 + cg * 4 + 3], acc.w);
    }
  } else {
    // ---- slow path: chunk crosses a segment boundary (~31 waves total) ----
    int curSeg = segA;
    for (int pb = p0; pb < p1; pb += 8) {
      int p = pb + sub;
      bool valid = (p < p1);
      int pc = valid ? p : p1 - 1;
      int sg = seg[pc];
      float4 xv = x4[(size_t)pc * 8 + cg];
      float d = fmaf(xv.x, w4.x, fmaf(xv.y, w4.y, fmaf(xv.z, w4.z, xv.w * w4.w)));
      float r = (xv.x + xv.y) + (xv.z + xv.w);
      d = sub8_sum(d);
      r = sub8_sum(r);
      float e = valid ? __expf(fmaf(c1, d + bv, c2) * (r * 0.03125f)) : 0.f;
      if (sg != curSeg) {
        atomicAdd(&pooled[curSeg * 32 + cg * 4 + 0], acc.x);
        atomicAdd(&pooled[curSeg * 32 + cg * 4 + 1], acc.y);
        atomicAdd(&pooled[curSeg * 32 + cg * 4 + 2], acc.z);
        atomicAdd(&pooled[curSeg * 32 + cg * 4 + 3], acc.w);
        acc = make_float4(0.f, 0.f, 0.f, 0.f);
        curSeg = sg;
      }
      acc.x = fmaf(xv.x, e, acc.x);
      acc.y = fmaf(xv.y, e, acc.y);
      acc.z = fmaf(xv.z, e, acc.z);
      acc.w = fmaf(xv.w, e, acc.w);
    }
    atomicAdd(&pooled[curSeg * 32 + cg * 4 + 0], acc.x);
    atomicAdd(&pooled[curSeg * 32 + cg * 4 + 1], acc.y);
    atomicAdd(&pooled[curSeg * 32 + cg * 4 + 2], acc.z);
    atomicAdd(&pooled[curSeg * 32 + cg * 4 + 3], acc.w);
  }
}

__global__ void k_final(const float* __restrict__ pooled, float* __restrict__ out) {
  int tid = threadIdx.x;                 // 1024 threads, one per out element
  float v = pooled[tid];
  float sq = v * v;
#pragma unroll
  for (int off = 16; off > 0; off >>= 1) sq += __shfl_xor(sq, off, 32);
  float norm = sqrtf(sq);
  out[tid] = v / fmaxf(norm, 1e-30f);    // z & len cancel under normalize
}

extern "C" void kernel_launch(void* const* d_in, const int* in_sizes, int n_in,
                              void* d_out, int out_size, void* d_ws, size_t ws_size,
                              hipStream_t stream) {
  const float* x     = (const float*)d_in[0];
  const float* w     = (const float*)d_in[1];
  const float* b     = (const float*)d_in[2];
  const float* gamma = (const float*)d_in[3];
  const float* beta  = (const float*)d_in[4];
  const int* seg     = (const int*)d_in[6];
  int N = in_sizes[6];          // 3,170,000
  float* out = (float*)d_out;

  char* ws = (char*)d_ws;
  double* sumsp  = (double*)ws;                        // NBLK*2 doubles (32 KB)
  float*  pooled = (float*)(ws + (size_t)NBLK * 16);   // 1024 floats

  const int nWaves = NBLK * (TPB / 64);      // 8192
  int chunk = (N + nWaves - 1) / nWaves;
  chunk = (chunk + 7) & ~7;                  // multiple of 8

  k_stats<<<NBLK, TPB, 0, stream>>>(x, w, b, sumsp, pooled, N);
  k_pool <<<NBLK, TPB, 0, stream>>>(x, seg, w, b, sumsp, gamma, beta, pooled, N, chunk);
  k_final<<<1, 1024, 0, stream>>>(pooled, out);
}